// Round 3
// baseline (352.087 us; speedup 1.0000x reference)
//
#include <hip/hip_runtime.h>
#include <hip/hip_bf16.h>

typedef __hip_bfloat16 bf16;

#define NGRAPH 16

// Dual-dtype element load (defensive): inputs are f32 per the reference, but
// detect bf16 from gamma (== ones): dword0 0x3F800000 (f32) vs 0x3F803F80 (bf16).
__device__ __forceinline__ float ldf(const void* p, size_t i, bool bf) {
  if (bf) return __bfloat162float(((const bf16*)p)[i]);
  return ((const float*)p)[i];
}
__device__ __forceinline__ bool detect_bf16(const void* gamma) {
  return *((const unsigned*)gamma) == 0x3F803F80u;
}

// ---------------- K1: graph offsets from sorted batch ids ----------------
__global__ void k_offsets(const int* __restrict__ batch, int N, int* __restrict__ offs) {
  int i = blockIdx.x * blockDim.x + threadIdx.x;
  if (i >= N) return;
  if (i == 0) { offs[0] = 0; offs[NGRAPH] = N; }
  else if (batch[i] != batch[i - 1]) offs[batch[i]] = i;
}

// ---------------- K2: QKV projection  [N,256] @ [256,768] -> f32 ws ----------------
__global__ __launch_bounds__(256) void k_qkv(const void* __restrict__ x,
                                             const void* __restrict__ Wqkv,
                                             const void* __restrict__ gamma,
                                             float* __restrict__ QKV, int N) {
  const bool bf = detect_bf16(gamma);
  __shared__ float xs[8][256];
  int t = threadIdx.x;
  int row0 = blockIdx.x * 8;
  #pragma unroll
  for (int i = 0; i < 8; ++i) {
    int row = row0 + i;
    xs[i][t] = (row < N) ? ldf(x, (size_t)row * 256 + t, bf) : 0.f;
  }
  __syncthreads();
  float acc0[8], acc1[8], acc2[8];
  #pragma unroll
  for (int r = 0; r < 8; ++r) acc0[r] = acc1[r] = acc2[r] = 0.f;
  for (int k = 0; k < 256; ++k) {
    float w0 = ldf(Wqkv, (size_t)k * 768 + t, bf);
    float w1 = ldf(Wqkv, (size_t)k * 768 + t + 256, bf);
    float w2 = ldf(Wqkv, (size_t)k * 768 + t + 512, bf);
    #pragma unroll
    for (int r = 0; r < 8; ++r) {
      float xv = xs[r][k];
      acc0[r] += xv * w0; acc1[r] += xv * w1; acc2[r] += xv * w2;
    }
  }
  #pragma unroll
  for (int r = 0; r < 8; ++r) {
    int row = row0 + r;
    if (row < N) {
      QKV[(size_t)row * 768 + t]       = acc0[r];
      QKV[(size_t)row * 768 + t + 256] = acc1[r];
      QKV[(size_t)row * 768 + t + 512] = acc2[r];
    }
  }
}

// ---------------- K3: ragged flash attention w/ RoPE distance bias ----------------
// block = (qtile of 8 queries, graph), 256 threads, all 8 heads fused.
__global__ __launch_bounds__(256) void k_attn(const void* __restrict__ pos,
                                              const void* __restrict__ freqs,
                                              const void* __restrict__ Wrope,
                                              const void* __restrict__ gamma,
                                              const float* __restrict__ QKV,
                                              const int* __restrict__ offs,
                                              float* __restrict__ O) {
  const bool bf = detect_bf16(gamma);
  __shared__ float Qt[8][256];       // pre-scaled Q rows
  __shared__ float S[8][8][37];      // [h][q][jj] pad->37: all phases <=2-way banks
  __shared__ float wf[16];
  __shared__ float Wr[128];          // W_rope [16][8]
  __shared__ float albuf[8][8];      // alpha per (h,q); reused for final l

  int b = blockIdx.y;
  int off = offs[b];
  int n = offs[b + 1] - off;
  int q0 = blockIdx.x * 8;
  if (q0 >= n) return;
  int t = threadIdx.x;

  const float scale = 0.17677669529663687f;  // 32^-0.5

  #pragma unroll
  for (int i = 0; i < 8; ++i) {
    int qrow = q0 + i;
    Qt[i][t] = (qrow < n) ? QKV[(size_t)(off + qrow) * 768 + t] * scale : 0.f;
  }
  if (t < 16)  wf[t] = fabsf(ldf(freqs, t, bf));
  if (t < 128) Wr[t] = ldf(Wrope, t, bf);

  float o[8];
  #pragma unroll
  for (int q = 0; q < 8; ++q) o[q] = 0.f;
  float mreg = -1e30f, lreg = 0.f;   // softmax state, owned by threads t<64
  int h3 = t >> 3, q3 = t & 7;       // phase3 mapping (64 tasks)
  int h5 = t >> 5, l5 = t & 31;      // phase2/4 mapping

  __syncthreads();

  for (int j0 = 0; j0 < n; j0 += 32) {
    // ---- phase 1: distance-RoPE bias into S (cos computed once per pair) ----
    {
      int q = t >> 5, jj = t & 31;
      int jg = j0 + jj;
      bool vj = jg < n;
      bool vq = (q0 + q) < n;
      float biasv[8];
      #pragma unroll
      for (int h = 0; h < 8; ++h) biasv[h] = 0.f;
      if (vj && vq) {
        int inode = off + q0 + q, jnode = off + jg;
        float dx = ldf(pos, (size_t)inode * 3 + 0, bf) - ldf(pos, (size_t)jnode * 3 + 0, bf);
        float dy = ldf(pos, (size_t)inode * 3 + 1, bf) - ldf(pos, (size_t)jnode * 3 + 1, bf);
        float dz = ldf(pos, (size_t)inode * 3 + 2, bf) - ldf(pos, (size_t)jnode * 3 + 2, bf);
        float dist = sqrtf(dx * dx + dy * dy + dz * dz);
        #pragma unroll
        for (int r = 0; r < 16; ++r) {
          float cv = __cosf(dist * wf[r]);
          #pragma unroll
          for (int h = 0; h < 8; ++h) biasv[h] += cv * Wr[r * 8 + h];
        }
      }
      #pragma unroll
      for (int h = 0; h < 8; ++h) S[h][q][jj] = vj ? biasv[h] : -1e30f;
    }
    __syncthreads();
    // ---- phase 2: S += Q.K^T (K segment register-cached across 8 queries) ----
    {
      int h = h5, jj = l5;
      int jg = j0 + jj;
      if (jg < n) {
        float kreg[32];
        const float4* kp = (const float4*)(QKV + (size_t)(off + jg) * 768 + 256 + h * 32);
        #pragma unroll
        for (int w = 0; w < 8; ++w) {
          float4 kk = kp[w];
          kreg[w * 4 + 0] = kk.x; kreg[w * 4 + 1] = kk.y;
          kreg[w * 4 + 2] = kk.z; kreg[w * 4 + 3] = kk.w;
        }
        #pragma unroll
        for (int q = 0; q < 8; ++q) {
          float dot = 0.f;
          #pragma unroll
          for (int d4 = 0; d4 < 8; ++d4) {
            float4 qv = *(const float4*)&Qt[q][h * 32 + d4 * 4];
            dot += qv.x * kreg[d4 * 4 + 0] + qv.y * kreg[d4 * 4 + 1]
                 + qv.z * kreg[d4 * 4 + 2] + qv.w * kreg[d4 * 4 + 3];
          }
          S[h][q][jj] += dot;
        }
      }
    }
    __syncthreads();
    // ---- phase 3: online softmax over this j-tile ----
    if (t < 64) {
      int h = h3, q = q3;
      float mrow = -1e30f;
      #pragma unroll
      for (int jj = 0; jj < 32; ++jj) mrow = fmaxf(mrow, S[h][q][jj]);
      float mnew = fmaxf(mreg, mrow);
      float a = __expf(mreg - mnew);
      float s = 0.f;
      #pragma unroll
      for (int jj = 0; jj < 32; ++jj) {
        float p = __expf(S[h][q][jj] - mnew);
        S[h][q][jj] = p;
        s += p;
      }
      lreg = lreg * a + s;
      mreg = mnew;
      albuf[h][q] = a;
    }
    __syncthreads();
    // ---- phase 4: O accumulate (rescale by alpha, then P.V) ----
    {
      int h = h5, dm = l5;
      #pragma unroll
      for (int q = 0; q < 8; ++q) o[q] *= albuf[h][q];
      int jmax = (n - j0 < 32) ? (n - j0) : 32;
      for (int jj = 0; jj < jmax; ++jj) {
        float v = QKV[(size_t)(off + j0 + jj) * 768 + 512 + h * 32 + dm];
        #pragma unroll
        for (int q = 0; q < 8; ++q) o[q] += S[h][q][jj] * v;
      }
    }
    __syncthreads();
  }

  if (t < 64) albuf[h3][q3] = lreg;
  __syncthreads();
  {
    int h = h5, dm = l5;
    #pragma unroll
    for (int q = 0; q < 8; ++q) {
      if (q0 + q < n) {
        O[(size_t)(off + q0 + q) * 256 + h * 32 + dm] = o[q] / albuf[h][q];
      }
    }
  }
}

// ---------------- K4: out-projection + residual + LayerNorm -> f32 out ----------------
__global__ __launch_bounds__(256) void k_outln(const void* __restrict__ x,
                                               const void* __restrict__ Wout,
                                               const void* __restrict__ gamma,
                                               const void* __restrict__ beta,
                                               const float* __restrict__ O,
                                               float* __restrict__ out, int N) {
  const bool bf = detect_bf16(gamma);
  __shared__ float Ot[8][256];
  __shared__ float yt[8][257];
  int t = threadIdx.x;
  int row0 = blockIdx.x * 8;
  #pragma unroll
  for (int i = 0; i < 8; ++i) {
    int row = row0 + i;
    Ot[i][t] = (row < N) ? O[(size_t)row * 256 + t] : 0.f;
  }
  __syncthreads();
  float acc[8];
  #pragma unroll
  for (int r = 0; r < 8; ++r) acc[r] = 0.f;
  for (int k = 0; k < 256; ++k) {
    float w = ldf(Wout, (size_t)k * 256 + t, bf);
    #pragma unroll
    for (int r = 0; r < 8; ++r) acc[r] += Ot[r][k] * w;
  }
  #pragma unroll
  for (int r = 0; r < 8; ++r) {
    int row = row0 + r;
    yt[r][t] = (row < N) ? ldf(x, (size_t)row * 256 + t, bf) + acc[r] : 0.f;
  }
  __syncthreads();
  int wv = t >> 6, lane = t & 63;
  #pragma unroll
  for (int rr = 0; rr < 2; ++rr) {
    int r = wv * 2 + rr;
    int row = row0 + r;
    float s = 0.f, ss = 0.f;
    #pragma unroll
    for (int k = 0; k < 4; ++k) {
      float v = yt[r][lane + 64 * k];
      s += v; ss += v * v;
    }
    #pragma unroll
    for (int m = 32; m >= 1; m >>= 1) {
      s += __shfl_xor(s, m);
      ss += __shfl_xor(ss, m);
    }
    float mean = s * (1.f / 256.f);
    float var = ss * (1.f / 256.f) - mean * mean;
    float rstd = rsqrtf(var + 1e-5f);
    if (row < N) {
      #pragma unroll
      for (int k = 0; k < 4; ++k) {
        int c = lane + 64 * k;
        float g = ldf(gamma, c, bf), bb = ldf(beta, c, bf);
        out[(size_t)row * 256 + c] = g * (yt[r][c] - mean) * rstd + bb;
      }
    }
  }
}

extern "C" void kernel_launch(void* const* d_in, const int* in_sizes, int n_in,
                              void* d_out, int out_size, void* d_ws, size_t ws_size,
                              hipStream_t stream) {
  (void)n_in; (void)out_size; (void)ws_size;
  const void* x     = d_in[0];
  const void* pos   = d_in[1];
  const int*  batch = (const int*)d_in[2];
  const void* Wqkv  = d_in[3];
  const void* Wout  = d_in[4];
  const void* freqs = d_in[5];
  const void* Wrope = d_in[6];
  const void* gamma = d_in[7];
  const void* beta  = d_in[8];
  float* out = (float*)d_out;

  int N = in_sizes[0] / 256;

  int*   offs = (int*)d_ws;
  float* QKV  = (float*)((char*)d_ws + 1024);           // [N][768] f32
  float* O    = QKV + (size_t)N * 768;                  // [N][256] f32

  k_offsets<<<(N + 255) / 256, 256, 0, stream>>>(batch, N, offs);
  k_qkv<<<(N + 7) / 8, 256, 0, stream>>>(x, Wqkv, gamma, QKV, N);
  k_attn<<<dim3(64, NGRAPH), 256, 0, stream>>>(pos, freqs, Wrope, gamma, QKV, offs, O);
  k_outln<<<(N + 7) / 8, 256, 0, stream>>>(x, Wout, gamma, beta, O, out, N);
}